// Round 10
// baseline (149.172 us; speedup 1.0000x reference)
//
#include <hip/hip_runtime.h>
#include <stdint.h>

typedef __attribute__((ext_vector_type(4)))  float f32x4;
typedef __attribute__((ext_vector_type(2)))  float f32x2;
typedef __attribute__((ext_vector_type(16))) float f32x16;
typedef __attribute__((ext_vector_type(8)))  short s16x8;
typedef __attribute__((ext_vector_type(4)))  short s16x4;

constexpr int kDIM = 1024;
constexpr int kD   = 64;
constexpr int kNT  = 2304;   // Nx + Nc

static __device__ __forceinline__ short f2bf(float f) {
  union { float f; uint32_t i; } x; x.f = f;
  uint32_t r = x.i + 0x7fffu + ((x.i >> 16) & 1u);
  return (short)(r >> 16);
}
static __device__ __forceinline__ uint32_t cvtpk(float lo, float hi) {
  uint32_t r;
  asm volatile("v_cvt_pk_bf16_f32 %0, %1, %2" : "=v"(r) : "v"(lo), "v"(hi));
  return r;
}
// async global->LDS, 16B per lane; LDS dest = wave-uniform base + lane*16
static __device__ __forceinline__ void gll16(const short* g, short* l) {
  __builtin_amdgcn_global_load_lds((const __attribute__((address_space(1))) void*)g,
                                   (__attribute__((address_space(3))) void*)l, 16, 0, 0);
}
#define FENCE() asm volatile("" ::: "memory")
#define WAITV8() asm volatile("s_waitcnt vmcnt(8)" ::: "memory")
#define WAITV4() asm volatile("s_waitcnt vmcnt(4)" ::: "memory")
#define WAITV0() asm volatile("s_waitcnt vmcnt(0)" ::: "memory")
#define WAITLGKM() do { asm volatile("s_waitcnt lgkmcnt(0)" ::: "memory"); \
                        __builtin_amdgcn_sched_barrier(0); } while (0)

// ---------- cast f32 -> bf16 (x and c in one launch) ----------
__global__ __launch_bounds__(256) void k_cast2(const float* __restrict__ x,
                                               short* __restrict__ xb,
                                               const float* __restrict__ c,
                                               short* __restrict__ cb, int nxb) {
  int b = blockIdx.x;
  const float* in = x; short* out = xb;
  if (b >= nxb) { in = c; out = cb; b -= nxb; }
  int i = (b * 256 + threadIdx.x) * 4;
  f32x4 v = *(const f32x4*)(in + i);
  s16x4 o; o[0] = f2bf(v[0]); o[1] = f2bf(v[1]); o[2] = f2bf(v[2]); o[3] = f2bf(v[3]);
  *(s16x4*)(out + i) = o;
}

// ---------- transpose+cast: W[K][N] f32 -> Wt[N][K] bf16, two weights per launch ----------
__global__ __launch_bounds__(256) void k_tcast2(const float* __restrict__ W0,
                                                short* __restrict__ Wt0,
                                                const float* __restrict__ W1,
                                                short* __restrict__ Wt1,
                                                int K, int N) {
  const float* W = blockIdx.z ? W1 : W0;
  short* Wt = blockIdx.z ? Wt1 : Wt0;
  __shared__ float tile[32][33];
  int n0 = blockIdx.x * 32, k0 = blockIdx.y * 32;
  int tx = threadIdx.x, ty = threadIdx.y;
#pragma unroll
  for (int i2 = 0; i2 < 4; ++i2) {
    int r = ty + 8 * i2;
    tile[r][tx] = W[(size_t)(k0 + r) * N + n0 + tx];
  }
  __syncthreads();
#pragma unroll
  for (int i2 = 0; i2 < 4; ++i2) {
    int r = ty + 8 * i2;
    Wt[(size_t)(n0 + r) * K + k0 + tx] = f2bf(tile[tx][r]);
  }
}

// ---------- GEMM: C = A * Wt^T + bias, 32x32x16 MFMA, two param-sets per launch ----------
// Double-buffered LDS + counted vmcnt. 2-D XCD chunking. Per k-step: 16 MFMA + 16 ds_read
// (vs 32+32 for 16x16). C-map: col=lane&31, row=(reg&3)+8(reg>>2)+4(lane>>5).
// epi==0: N=3072, fused RMSNorm on q/k heads (q gets 0.125*log2e), v transposed+permuted
// epi==1: N=1024, f32 rows to outp
__global__ __launch_bounds__(256, 2) void k_gemm(
    const short* A0, const short* Wt0, const float* bias0,
    const float* sq0, const float* sk0,
    const short* A1, const short* Wt1, const float* bias1,
    const float* sq1, const float* sk1,
    short* outq, short* outk, short* outvt,
    float* outp0, float* outp1,
    int rpbs0, int arstride0, int aoff0, int posoff0,
    int rpbs1, int arstride1, int aoff1, int posoff1,
    int ybreak, int epi, int nx) {
  __shared__ __align__(16) short SH[32768];   // 64 KB
  short* As0 = SH;          short* As1 = SH + 8192;
  short* Bs0 = SH + 16384;  short* Bs1 = SH + 24576;
  const int t = threadIdx.x;
  const int lane = t & 63, w = t >> 6;
  const int h = lane >> 5, q31 = lane & 31;
  const int wm = w >> 1, wn = w & 1;

  // 2-D XCD chunk decode
  int lin = blockIdx.x;
  int xcd = lin & 7, kk = lin >> 3;
  int by = (xcd & 3) * 9 + kk % 9;
  int bx = (xcd >> 2) * (nx >> 1) + kk / 9;

  const short* A; const short* Wt; const float* bias;
  const float* sq; const float* sk; float* outp;
  int rpbs, arstride, aoff, posoff, my;
  if (by < ybreak) {
    A = A0; Wt = Wt0; bias = bias0; sq = sq0; sk = sk0; outp = outp0;
    rpbs = rpbs0; arstride = arstride0; aoff = aoff0; posoff = posoff0; my = by;
  } else {
    A = A1; Wt = Wt1; bias = bias1; sq = sq1; sk = sk1; outp = outp1;
    rpbs = rpbs1; arstride = arstride1; aoff = aoff1; posoff = posoff1; my = by - ybreak;
  }
  const int m0 = my * 128, n0 = bx * 128;

  const short* aptr[4]; const short* bptr[4];
  int wofs[4];
#pragma unroll
  for (int it = 0; it < 4; ++it) {
    int slot = t + 256 * it;
    int row = slot >> 3, gp = slot & 7;
    int gl = gp ^ (row & 7);               // pre-swizzled source group
    int i = m0 + row;
    int arow = (i >> rpbs) * arstride + aoff + (i & ((1 << rpbs) - 1));
    aptr[it] = A + (size_t)arow * kDIM + 8 * gl;
    bptr[it] = Wt + (size_t)(n0 + row) * kDIM + 8 * gl;
    wofs[it] = (256 * it + 64 * w) * 8;
  }

  // hoisted fragment offsets: group G = 2s + h of row, XOR-descrambled
  int ao_[2][4], bo_[2][4];
#pragma unroll
  for (int mr = 0; mr < 2; ++mr) {
    int rowa = wm * 64 + mr * 32 + q31;
    int rowb = wn * 64 + mr * 32 + q31;
#pragma unroll
    for (int s = 0; s < 4; ++s) {
      ao_[mr][s] = rowa * 64 + (((2 * s + h) ^ (rowa & 7)) * 8);
      bo_[mr][s] = rowb * 64 + (((2 * s + h) ^ (rowb & 7)) * 8);
    }
  }

  f32x16 acc[2][2] = {};

  auto STAGE = [&](short* Asd, short* Bsd) {
#pragma unroll
    for (int it = 0; it < 4; ++it) {
      gll16(aptr[it], Asd + wofs[it]);
      gll16(bptr[it], Bsd + wofs[it]);
      aptr[it] += 64; bptr[it] += 64;
    }
  };

  auto kstep = [&](const short* Ab, const short* Bb, short* Asd, short* Bsd,
                   bool last, bool pref) {
    if (last) WAITV0(); else WAITV8();
    __builtin_amdgcn_s_barrier();
    FENCE();
#pragma unroll
    for (int s = 0; s < 4; ++s) {
      s16x8 a0 = *(const s16x8*)(Ab + ao_[0][s]);
      s16x8 a1 = *(const s16x8*)(Ab + ao_[1][s]);
      s16x8 b0 = *(const s16x8*)(Bb + bo_[0][s]);
      s16x8 b1 = *(const s16x8*)(Bb + bo_[1][s]);
      acc[0][0] = __builtin_amdgcn_mfma_f32_32x32x16_bf16(a0, b0, acc[0][0], 0, 0, 0);
      acc[0][1] = __builtin_amdgcn_mfma_f32_32x32x16_bf16(a0, b1, acc[0][1], 0, 0, 0);
      acc[1][0] = __builtin_amdgcn_mfma_f32_32x32x16_bf16(a1, b0, acc[1][0], 0, 0, 0);
      acc[1][1] = __builtin_amdgcn_mfma_f32_32x32x16_bf16(a1, b1, acc[1][1], 0, 0, 0);
    }
    FENCE();
    __builtin_amdgcn_s_barrier();
    FENCE();
    if (pref) STAGE(Asd, Bsd);
  };

  STAGE(As0, Bs0);
  STAGE(As1, Bs1);
  for (int pp = 0; pp < 8; ++pp) {
    kstep(As0, Bs0, As0, Bs0, false,   pp < 7);
    kstep(As1, Bs1, As1, Bs1, pp == 7, pp < 7);
  }

  // ---- epilogue: per-wave LDS transpose (reuse staging LDS; own region only) ----
  const int rpbm = (1 << rpbs) - 1;
  float* Ep = (float*)SH + w * 4096;   // 16 KB per wave, [64 r][64 c] xor-swizzled (gran-2)

  if (epi == 1) {
#pragma unroll
    for (int mr = 0; mr < 2; ++mr)
#pragma unroll
      for (int nr = 0; nr < 2; ++nr) {
        float bj = bias[n0 + wn * 64 + nr * 32 + q31];
        int dl = nr * 32 + q31;
#pragma unroll
        for (int r = 0; r < 16; ++r) {
          int row = mr * 32 + (r & 3) + 8 * (r >> 2) + 4 * h;
          Ep[row * 64 + (dl ^ ((row & 15) << 1))] = acc[mr][nr][r] + bj;
        }
      }
    WAITLGKM();
#pragma unroll
    for (int p2 = 0; p2 < 16; ++p2) {
      int r = 4 * p2 + (lane >> 4);
      int ch = lane & 15;
      int i = m0 + wm * 64 + r;
      f32x2 a = *(const f32x2*)&Ep[r * 64 + ((ch * 4) ^ ((r & 15) << 1))];
      f32x2 b2 = *(const f32x2*)&Ep[r * 64 + ((ch * 4 + 2) ^ ((r & 15) << 1))];
      f32x4 o; o[0] = a[0]; o[1] = a[1]; o[2] = b2[0]; o[3] = b2[1];
      *(f32x4*)(outp + (size_t)i * 1024 + n0 + wn * 64 + ch * 4) = o;
    }
    return;
  }

  const int eblk = (n0 + wn * 64) >> 10;   // wave-uniform: 0=q, 1=k, 2=v
  const int hh = ((n0 + wn * 64) >> 6) & 15;
  if (eblk == 2) {
    // v: LDS holds [64 d][64 pin'] with the pos-permute (bits 2<->3 swap) folded in
#pragma unroll
    for (int mr = 0; mr < 2; ++mr)
#pragma unroll
      for (int nr = 0; nr < 2; ++nr) {
        float bj = bias[n0 + wn * 64 + nr * 32 + q31];
        int dl = nr * 32 + q31;
#pragma unroll
        for (int r = 0; r < 16; ++r) {
          int pin = mr * 32 + (r & 3) + 8 * (r >> 2) + 4 * h;
          int pp2 = (pin & 51) | ((pin & 4) << 1) | ((pin & 8) >> 1);
          Ep[dl * 64 + (pp2 ^ ((dl & 15) << 1))] = acc[mr][nr][r] + bj;
        }
      }
    WAITLGKM();
    int i0 = m0 + wm * 64;
    int b = i0 >> rpbs;
    int posb = (i0 & rpbm) + posoff;
#pragma unroll
    for (int p2 = 0; p2 < 8; ++p2) {
      int dl = 8 * p2 + (lane >> 3);
      int ch = lane & 7;
      union { uint32_t u[4]; s16x8 v; } o;
#pragma unroll
      for (int j = 0; j < 4; ++j) {
        f32x2 rd = *(const f32x2*)&Ep[dl * 64 + ((ch * 8 + 2 * j) ^ ((dl & 15) << 1))];
        o.u[j] = cvtpk(rd[0], rd[1]);
      }
      *(s16x8*)(outvt + ((size_t)((b * 16 + hh) * 64 + dl)) * kNT + posb + ch * 8) = o.v;
    }
  } else {
    const float* sv = (eblk == 0) ? sq : sk;
    short* dstb = (eblk == 0) ? outq : outk;
    const float post = (eblk == 0) ? 0.125f * 1.44269504f : 1.0f;
    float sl[2], bj2[2];
#pragma unroll
    for (int nr = 0; nr < 2; ++nr) {
      bj2[nr] = bias[n0 + wn * 64 + nr * 32 + q31];
      sl[nr] = sv[nr * 32 + q31] * post;
    }
#pragma unroll
    for (int mr = 0; mr < 2; ++mr)
#pragma unroll
      for (int r = 0; r < 16; ++r) {
        float v0 = acc[mr][0][r] + bj2[0];
        float v1 = acc[mr][1][r] + bj2[1];
        float ss = __builtin_fmaf(v1, v1, v0 * v0);
        ss += __shfl_xor(ss, 1);  ss += __shfl_xor(ss, 2);
        ss += __shfl_xor(ss, 4);  ss += __shfl_xor(ss, 8);
        ss += __shfl_xor(ss, 16);
        float f = rsqrtf(ss * (1.f / 64.f) + 1e-6f);
        int row = mr * 32 + (r & 3) + 8 * (r >> 2) + 4 * h;
        Ep[row * 64 + ((q31) ^ ((row & 15) << 1))] = v0 * f * sl[0];
        Ep[row * 64 + ((32 + q31) ^ ((row & 15) << 1))] = v1 * f * sl[1];
      }
    WAITLGKM();
#pragma unroll
    for (int p2 = 0; p2 < 8; ++p2) {
      int r = 8 * p2 + (lane >> 3);
      int ch = lane & 7;
      int i = m0 + wm * 64 + r;
      int b = i >> rpbs;
      int pos = (i & rpbm) + posoff;
      union { uint32_t u[4]; s16x8 v; } o;
#pragma unroll
      for (int j = 0; j < 4; ++j) {
        f32x2 rd = *(const f32x2*)&Ep[r * 64 + ((ch * 8 + 2 * j) ^ ((r & 15) << 1))];
        o.u[j] = cvtpk(rd[0], rd[1]);
      }
      *(s16x8*)(dstb + ((size_t)((b * 16 + hh) * kNT + pos)) * 64 + ch * 8) = o.v;
    }
  }
}

// ---------- Flash attention: 4 waves x 32 q (QBLK=128), 32x32x16 MFMA ----------
// Same verified layout as round 9; restructured for register pressure:
// QK+softmax processed per 32-kv row-group (st live = 16 regs), exp2 fused into
// cvtpk (no p[16] array), __launch_bounds__(256,2) so nothing spills.
__global__ __launch_bounds__(256, 2) void k_attn(
    const short* __restrict__ Q, const short* __restrict__ K,
    const short* __restrict__ Vt, short* __restrict__ Ao) {
  __shared__ __align__(16) short S[16384];  // 32 KB: K dbuf [0,8192), V dbuf [8192,16384)
  const int t = threadIdx.x;
  const int lane = t & 63, w = t >> 6;      // w 0..3
  const int h = lane >> 5, q31 = lane & 31;
  const int lin = blockIdx.x;
  const int idx = lin >> 3;
  const int bh = (lin & 7) * 4 + idx / 18;
  const int q0 = (idx % 18) * 128;

  // Q B-fragments (q = q0 + 32w + q31): frag a holds d = 16a + 8h + j
  const short* qrow = Q + ((size_t)bh * kNT + q0 + 32 * w + q31) * kD;
  s16x8 qf[4];
#pragma unroll
  for (int a = 0; a < 4; ++a)
    qf[a] = *(const s16x8*)(qrow + 16 * a + 8 * h);

  // staging: 512 slots per matrix per tile, 2 per thread (4 gll/wave/tile)
  const short* kptr[2]; const short* vptr[2];
  int sb[2];
#pragma unroll
  for (int it = 0; it < 2; ++it) {
    int slot = t + 256 * it;
    int row = slot >> 3, gp = slot & 7;
    int gl = gp ^ (row & 7);
    kptr[it] = K + ((size_t)bh * kNT + row) * kD + 8 * gl;
    vptr[it] = Vt + ((size_t)bh * kD + row) * kNT + 8 * gl;
    sb[it] = (256 * it + 64 * w) * 8;
  }

  // hoisted LDS read offsets: frag (rg, s): row 32rg+q31, group 2s+h (shared K/V)
  int ko[2][4];
#pragma unroll
  for (int rg = 0; rg < 2; ++rg) {
    int row = 32 * rg + q31;
#pragma unroll
    for (int s = 0; s < 4; ++s)
      ko[rg][s] = row * 64 + (((2 * s + h) ^ (row & 7)) * 8);
  }

  f32x16 ot0 = {}, ot1 = {};
  float l = 0.f;
  short* Kb0 = S;          short* Kb1 = S + 4096;
  short* Vb0 = S + 8192;   short* Vb1 = S + 12288;

  auto STAGE = [&](short* kst, short* vst) {
#pragma unroll
    for (int it = 0; it < 2; ++it) {
      gll16(kptr[it], kst + sb[it]); kptr[it] += 64 * kD;
      gll16(vptr[it], vst + sb[it]); vptr[it] += 64;
    }
  };

  auto tile = [&](const short* Kb, const short* Vb, short* kst, short* vst,
                  bool last, bool pref) {
    if (last) WAITV0(); else WAITV4();
    __builtin_amdgcn_s_barrier();
    FENCE();
    s16x8 pf[4];
    float rs = 0.f;
    // per 32-kv row-group: QK (4 MFMA) then softmax+pack (st live = 16 regs)
#pragma unroll
    for (int rg = 0; rg < 2; ++rg) {
      f32x16 st = {};
      __builtin_amdgcn_s_setprio(1);
#pragma unroll
      for (int a = 0; a < 4; ++a) {
        s16x8 kf = *(const s16x8*)(Kb + ko[rg][a]);
        st = __builtin_amdgcn_mfma_f32_32x32x16_bf16(kf, qf[a], st, 0, 0, 0);
      }
      __builtin_amdgcn_s_setprio(0);
#pragma unroll
      for (int mh = 0; mh < 2; ++mh) {
        union { uint32_t u[4]; s16x8 v; } pk;
#pragma unroll
        for (int i = 0; i < 4; ++i) {
          float e0 = __builtin_amdgcn_exp2f(st[8 * mh + 2 * i]);
          float e1 = __builtin_amdgcn_exp2f(st[8 * mh + 2 * i + 1]);
          rs += e0 + e1;
          pk.u[i] = cvtpk(e0, e1);
        }
        pf[2 * rg + mh] = pk.v;
      }
    }
    l += rs;
    // O^T += V^T * P^T : d row-groups (ot0/ot1), kv k-slices m
    __builtin_amdgcn_s_setprio(1);
#pragma unroll
    for (int m = 0; m < 4; ++m) {
      s16x8 vf0 = *(const s16x8*)(Vb + ko[0][m]);
      s16x8 vf1 = *(const s16x8*)(Vb + ko[1][m]);
      ot0 = __builtin_amdgcn_mfma_f32_32x32x16_bf16(vf0, pf[m], ot0, 0, 0, 0);
      ot1 = __builtin_amdgcn_mfma_f32_32x32x16_bf16(vf1, pf[m], ot1, 0, 0, 0);
    }
    __builtin_amdgcn_s_setprio(0);
    FENCE();
    __builtin_amdgcn_s_barrier();
    FENCE();
    if (pref) STAGE(kst, vst);
  };

  STAGE(Kb0, Vb0);
  STAGE(Kb1, Vb1);
  for (int pp = 0; pp < 18; ++pp) {
    tile(Kb0, Vb0, Kb0, Vb0, false,    pp < 17);
    tile(Kb1, Vb1, Kb1, Vb1, pp == 17, pp < 17);
  }

  // each lane holds half the kv-sum for its q; combine across half-waves once
  l += __shfl_xor(l, 32);
  float rl = 1.f / l;

  // epilogue: O^T regs -> LDS [128 q][64 d] f32 (XOR-swz), coalesced bf16 store
  __syncthreads();
  float* Os = (float*)S;   // 8192 floats = 32 KB
  const int R = 32 * w + q31;
#pragma unroll
  for (int rg = 0; rg < 2; ++rg)
#pragma unroll
    for (int rr = 0; rr < 4; ++rr) {
      int d0 = 32 * rg + 8 * rr + 4 * h;
      f32x4 v4;
#pragma unroll
      for (int j = 0; j < 4; ++j)
        v4[j] = (rg ? ot1[4 * rr + j] : ot0[4 * rr + j]) * rl;
      *(f32x4*)&Os[R * 64 + (d0 ^ ((R & 7) << 3))] = v4;
    }
  __syncthreads();
  {
    int b = bh >> 4, hh = bh & 15;
#pragma unroll
    for (int rep = 0; rep < 2; ++rep) {
      int idx2 = t + 256 * rep;
      int q = idx2 >> 2, c4 = idx2 & 3;
      float vals[16];
#pragma unroll
      for (int i = 0; i < 4; ++i) {
        f32x4 rd = *(const f32x4*)&Os[q * 64 + (((c4 * 16 + 4 * i) ^ ((q & 7) << 3)))];
        vals[4 * i + 0] = rd[0]; vals[4 * i + 1] = rd[1];
        vals[4 * i + 2] = rd[2]; vals[4 * i + 3] = rd[3];
      }
      union { uint32_t u[4]; s16x8 v; } o0, o1;
      o0.u[0] = cvtpk(vals[0], vals[1]);   o0.u[1] = cvtpk(vals[2], vals[3]);
      o0.u[2] = cvtpk(vals[4], vals[5]);   o0.u[3] = cvtpk(vals[6], vals[7]);
      o1.u[0] = cvtpk(vals[8], vals[9]);   o1.u[1] = cvtpk(vals[10], vals[11]);
      o1.u[2] = cvtpk(vals[12], vals[13]); o1.u[3] = cvtpk(vals[14], vals[15]);
      short* dst = Ao + ((size_t)b * kNT + q0 + q) * kDIM + hh * kD + c4 * 16;
      *(s16x8*)dst = o0.v;
      *(s16x8*)(dst + 8) = o1.v;
    }
  }
}

extern "C" void kernel_launch(void* const* d_in, const int* in_sizes, int n_in,
                              void* d_out, int out_size, void* d_ws, size_t ws_size,
                              hipStream_t stream) {
  const float* x   = (const float*)d_in[0];
  const float* c   = (const float*)d_in[1];
  const float* wqx = (const float*)d_in[2];
  const float* bqx = (const float*)d_in[3];
  const float* wqc = (const float*)d_in[4];
  const float* bqc = (const float*)d_in[5];
  const float* sqx = (const float*)d_in[6];
  const float* skx = (const float*)d_in[7];
  const float* sqc = (const float*)d_in[8];
  const float* skc = (const float*)d_in[9];
  const float* wpx = (const float*)d_in[10];
  const float* bpx = (const float*)d_in[11];
  const float* wpc = (const float*)d_in[12];
  const float* bpc = (const float*)d_in[13];
  float* out = (float*)d_out;

  char* p = (char*)d_ws;
  short* xb   = (short*)p; p += (size_t)4096 * 1024 * 2;
  short* cb   = (short*)p; p += (size_t)512 * 1024 * 2;
  short* wqxt = (short*)p; p += (size_t)3072 * 1024 * 2;
  short* wqct = (short*)p; p += (size_t)3072 * 1024 * 2;
  short* wpxt = (short*)p; p += (size_t)1024 * 1024 * 2;
  short* wpct = (short*)p; p += (size_t)1024 * 1024 * 2;
  short* qb   = (short*)p; p += (size_t)32 * 2304 * 64 * 2;
  short* kb   = (short*)p; p += (size_t)32 * 2304 * 64 * 2;
  short* vtb  = (short*)p; p += (size_t)32 * 64 * 2304 * 2;
  short* ao   = (short*)p; p += (size_t)2 * 2304 * 1024 * 2;

  k_cast2<<<4608, 256, 0, stream>>>(x, xb, c, cb, 4096);
  k_tcast2<<<dim3(96, 32, 2), dim3(32, 8), 0, stream>>>(wqx, wqxt, wqc, wqct, 1024, 3072);
  k_tcast2<<<dim3(32, 32, 2), dim3(32, 8), 0, stream>>>(wpx, wpxt, wpc, wpct, 1024, 1024);

  // QKV projections (+bias, fused RMSNorm; q pre-scaled by 0.125*log2e)
  k_gemm<<<864, 256, 0, stream>>>(
      xb, wqxt, bqx, sqx, skx,
      cb, wqct, bqc, sqc, skc,
      qb, kb, vtb, nullptr, nullptr,
      11, 2048, 0, 0,
      8, 256, 0, 2048,
      32, 0, 24);

  k_attn<<<576, 256, 0, stream>>>(qb, kb, vtb, ao);

  // output projections (f32 + bias) straight into d_out
  k_gemm<<<288, 256, 0, stream>>>(
      ao, wpxt, bpx, nullptr, nullptr,
      ao, wpct, bpc, nullptr, nullptr,
      nullptr, nullptr, nullptr, out, out + (size_t)4096 * 1024,
      11, 2304, 0, 0,
      8, 2304, 2048, 0,
      32, 1, 8);
}

// Round 14
// 125.403 us; speedup vs baseline: 1.1895x; 1.1895x over previous
//
#include <hip/hip_runtime.h>
#include <stdint.h>

typedef __attribute__((ext_vector_type(4)))  float f32x4;
typedef __attribute__((ext_vector_type(2)))  float f32x2;
typedef __attribute__((ext_vector_type(8)))  short s16x8;
typedef __attribute__((ext_vector_type(4)))  short s16x4;

constexpr int kDIM = 1024;
constexpr int kD   = 64;
constexpr int kNT  = 2304;   // Nx + Nc

static __device__ __forceinline__ short f2bf(float f) {
  union { float f; uint32_t i; } x; x.f = f;
  uint32_t r = x.i + 0x7fffu + ((x.i >> 16) & 1u);
  return (short)(r >> 16);
}
static __device__ __forceinline__ uint32_t cvtpk(float lo, float hi) {
  uint32_t r;
  asm volatile("v_cvt_pk_bf16_f32 %0, %1, %2" : "=v"(r) : "v"(lo), "v"(hi));
  return r;
}
// async global->LDS, 16B per lane; LDS dest = wave-uniform base + lane*16
static __device__ __forceinline__ void gll16(const short* g, short* l) {
  __builtin_amdgcn_global_load_lds((const __attribute__((address_space(1))) void*)g,
                                   (__attribute__((address_space(3))) void*)l, 16, 0, 0);
}
#define FENCE() asm volatile("" ::: "memory")
#define WAITV8() asm volatile("s_waitcnt vmcnt(8)" ::: "memory")
#define WAITV4() asm volatile("s_waitcnt vmcnt(4)" ::: "memory")
#define WAITV0() asm volatile("s_waitcnt vmcnt(0)" ::: "memory")
#define WAITLGKM() do { asm volatile("s_waitcnt lgkmcnt(0)" ::: "memory"); \
                        __builtin_amdgcn_sched_barrier(0); } while (0)

// ---------- cast f32 -> bf16 (x and c in one launch) ----------
__global__ __launch_bounds__(256) void k_cast2(const float* __restrict__ x,
                                               short* __restrict__ xb,
                                               const float* __restrict__ c,
                                               short* __restrict__ cb, int nxb) {
  int b = blockIdx.x;
  const float* in = x; short* out = xb;
  if (b >= nxb) { in = c; out = cb; b -= nxb; }
  int i = (b * 256 + threadIdx.x) * 4;
  f32x4 v = *(const f32x4*)(in + i);
  s16x4 o; o[0] = f2bf(v[0]); o[1] = f2bf(v[1]); o[2] = f2bf(v[2]); o[3] = f2bf(v[3]);
  *(s16x4*)(out + i) = o;
}

// ---------- transpose+cast: W[K][N] f32 -> Wt[N][K] bf16, two weights per launch ----------
__global__ __launch_bounds__(256) void k_tcast2(const float* __restrict__ W0,
                                                short* __restrict__ Wt0,
                                                const float* __restrict__ W1,
                                                short* __restrict__ Wt1,
                                                int K, int N) {
  const float* W = blockIdx.z ? W1 : W0;
  short* Wt = blockIdx.z ? Wt1 : Wt0;
  __shared__ float tile[32][33];
  int n0 = blockIdx.x * 32, k0 = blockIdx.y * 32;
  int tx = threadIdx.x, ty = threadIdx.y;
#pragma unroll
  for (int i2 = 0; i2 < 4; ++i2) {
    int r = ty + 8 * i2;
    tile[r][tx] = W[(size_t)(k0 + r) * N + n0 + tx];
  }
  __syncthreads();
#pragma unroll
  for (int i2 = 0; i2 < 4; ++i2) {
    int r = ty + 8 * i2;
    Wt[(size_t)(n0 + r) * K + k0 + tx] = f2bf(tile[tx][r]);
  }
}

// ---------- GEMM: C = A * Wt^T + bias, 16x16x32 MFMA (R8-proven) ----------
// Double-buffered LDS + counted vmcnt. 2-D XCD chunking. All epilogues go through
// a per-wave LDS transpose -> fully coalesced 16B-per-lane stores.
// epi==0: N=3072, fused RMSNorm on q/k heads (q gets 0.125*log2e), v transposed+permuted
// epi==1: N=1024, f32 rows to outp
__global__ __launch_bounds__(256, 2) void k_gemm(
    const short* A0, const short* Wt0, const float* bias0,
    const float* sq0, const float* sk0,
    const short* A1, const short* Wt1, const float* bias1,
    const float* sq1, const float* sk1,
    short* outq, short* outk, short* outvt,
    float* outp0, float* outp1,
    int rpbs0, int arstride0, int aoff0, int posoff0,
    int rpbs1, int arstride1, int aoff1, int posoff1,
    int ybreak, int epi, int nx) {
  __shared__ __align__(16) short SH[32768];   // 64 KB
  short* As0 = SH;          short* As1 = SH + 8192;
  short* Bs0 = SH + 16384;  short* Bs1 = SH + 24576;
  const int t = threadIdx.x;
  const int lane = t & 63, w = t >> 6;
  const int g = lane >> 4, r15 = lane & 15;
  const int wm = w >> 1, wn = w & 1;

  // 2-D XCD chunk decode
  int lin = blockIdx.x;
  int xcd = lin & 7, kk = lin >> 3;
  int by = (xcd & 3) * 9 + kk % 9;
  int bx = (xcd >> 2) * (nx >> 1) + kk / 9;

  const short* A; const short* Wt; const float* bias;
  const float* sq; const float* sk; float* outp;
  int rpbs, arstride, aoff, posoff, my;
  if (by < ybreak) {
    A = A0; Wt = Wt0; bias = bias0; sq = sq0; sk = sk0; outp = outp0;
    rpbs = rpbs0; arstride = arstride0; aoff = aoff0; posoff = posoff0; my = by;
  } else {
    A = A1; Wt = Wt1; bias = bias1; sq = sq1; sk = sk1; outp = outp1;
    rpbs = rpbs1; arstride = arstride1; aoff = aoff1; posoff = posoff1; my = by - ybreak;
  }
  const int m0 = my * 128, n0 = bx * 128;

  const short* aptr[4]; const short* bptr[4];
  int wofs[4];
#pragma unroll
  for (int it = 0; it < 4; ++it) {
    int slot = t + 256 * it;
    int row = slot >> 3, gp = slot & 7;
    int gl = gp ^ (row & 7);               // pre-swizzled source group
    int i = m0 + row;
    int arow = (i >> rpbs) * arstride + aoff + (i & ((1 << rpbs) - 1));
    aptr[it] = A + (size_t)arow * kDIM + 8 * gl;
    bptr[it] = Wt + (size_t)(n0 + row) * kDIM + 8 * gl;
    wofs[it] = (256 * it + 64 * w) * 8;
  }

  f32x4 acc[4][4] = {};

  auto STAGE = [&](short* Asd, short* Bsd) {
#pragma unroll
    for (int it = 0; it < 4; ++it) {
      gll16(aptr[it], Asd + wofs[it]);
      gll16(bptr[it], Bsd + wofs[it]);
      aptr[it] += 64; bptr[it] += 64;
    }
  };

  auto kstep = [&](const short* Ab, const short* Bb, short* Asd, short* Bsd,
                   bool last, bool pref) {
    if (last) WAITV0(); else WAITV8();
    __builtin_amdgcn_s_barrier();
    FENCE();
#pragma unroll
    for (int ks = 0; ks < 2; ++ks) {
      s16x8 af[4], bfr[4];
#pragma unroll
      for (int mf = 0; mf < 4; ++mf) {
        int row = wm * 64 + mf * 16 + r15;
        af[mf] = *(const s16x8*)(Ab + row * 64 + (((g + 4 * ks) ^ (row & 7)) * 8));
      }
#pragma unroll
      for (int nf = 0; nf < 4; ++nf) {
        int row = wn * 64 + nf * 16 + r15;
        bfr[nf] = *(const s16x8*)(Bb + row * 64 + (((g + 4 * ks) ^ (row & 7)) * 8));
      }
#pragma unroll
      for (int mf = 0; mf < 4; ++mf)
#pragma unroll
        for (int nf = 0; nf < 4; ++nf)
          acc[mf][nf] = __builtin_amdgcn_mfma_f32_16x16x32_bf16(af[mf], bfr[nf], acc[mf][nf], 0, 0, 0);
    }
    FENCE();
    __builtin_amdgcn_s_barrier();
    FENCE();
    if (pref) STAGE(Asd, Bsd);
  };

  STAGE(As0, Bs0);
  STAGE(As1, Bs1);
  for (int pp = 0; pp < 8; ++pp) {
    kstep(As0, Bs0, As0, Bs0, false,   pp < 7);
    kstep(As1, Bs1, As1, Bs1, pp == 7, pp < 7);
  }

  // ---- epilogue: per-wave LDS transpose (reuse staging LDS; own region only) ----
  const int rpbm = (1 << rpbs) - 1;
  float* Ep = (float*)SH + w * 4096;   // 16 KB per wave, [64 r][64 c] xor-swizzled (gran-2)

  if (epi == 1) {
#pragma unroll
    for (int mf = 0; mf < 4; ++mf)
#pragma unroll
      for (int nf = 0; nf < 4; ++nf) {
        f32x4 v = acc[mf][nf];
        float bj = bias[n0 + wn * 64 + nf * 16 + r15];
        int dl = nf * 16 + r15;
#pragma unroll
        for (int rg = 0; rg < 4; ++rg) {
          int r = mf * 16 + 4 * g + rg;
          Ep[r * 64 + (dl ^ ((r & 15) << 1))] = v[rg] + bj;
        }
      }
    WAITLGKM();
#pragma unroll
    for (int p2 = 0; p2 < 16; ++p2) {
      int r = 4 * p2 + (lane >> 4);
      int ch = lane & 15;
      int i = m0 + wm * 64 + r;
      f32x2 a = *(const f32x2*)&Ep[r * 64 + ((ch * 4) ^ ((r & 15) << 1))];
      f32x2 b2 = *(const f32x2*)&Ep[r * 64 + ((ch * 4 + 2) ^ ((r & 15) << 1))];
      f32x4 o; o[0] = a[0]; o[1] = a[1]; o[2] = b2[0]; o[3] = b2[1];
      *(f32x4*)(outp + (size_t)i * 1024 + n0 + wn * 64 + ch * 4) = o;
    }
    return;
  }

  const int eblk = (n0 + wn * 64) >> 10;   // wave-uniform: 0=q, 1=k, 2=v
  const int hh = ((n0 + wn * 64) >> 6) & 15;
  if (eblk == 2) {
    // v: LDS holds [64 d][64 pin'] with the pos-permute folded into the write
#pragma unroll
    for (int mf = 0; mf < 4; ++mf)
#pragma unroll
      for (int nf = 0; nf < 4; ++nf) {
        f32x4 v = acc[mf][nf];
        float bj = bias[n0 + wn * 64 + nf * 16 + r15];
        int dl = nf * 16 + r15;
#pragma unroll
        for (int rg = 0; rg < 4; ++rg) {
          int pin = mf * 16 + 4 * g + rg;
          int pp2 = (pin & 32) | (((pin >> 2) & 3) << 3) |
                    (((pin >> 4) & 1) << 2) | (pin & 3);
          Ep[dl * 64 + (pp2 ^ ((dl & 15) << 1))] = v[rg] + bj;
        }
      }
    WAITLGKM();
    int i0 = m0 + wm * 64;
    int b = i0 >> rpbs;
    int posb = (i0 & rpbm) + posoff;
#pragma unroll
    for (int p2 = 0; p2 < 8; ++p2) {
      int dl = 8 * p2 + (lane >> 3);
      int ch = lane & 7;
      union { uint32_t u[4]; s16x8 v; } o;
#pragma unroll
      for (int j = 0; j < 4; ++j) {
        f32x2 rd = *(const f32x2*)&Ep[dl * 64 + ((ch * 8 + 2 * j) ^ ((dl & 15) << 1))];
        o.u[j] = cvtpk(rd[0], rd[1]);
      }
      *(s16x8*)(outvt + ((size_t)((b * 16 + hh) * 64 + dl)) * kNT + posb + ch * 8) = o.v;
    }
  } else {
    const float* sv = (eblk == 0) ? sq : sk;
    short* dstb = (eblk == 0) ? outq : outk;
    const float post = (eblk == 0) ? 0.125f * 1.44269504f : 1.0f;
    float sl[4], bj4[4];
#pragma unroll
    for (int nf = 0; nf < 4; ++nf) {
      bj4[nf] = bias[n0 + wn * 64 + nf * 16 + r15];
      sl[nf] = sv[nf * 16 + r15] * post;
    }
#pragma unroll
    for (int mf = 0; mf < 4; ++mf) {
      float vb[4][4];
#pragma unroll
      for (int nf = 0; nf < 4; ++nf)
#pragma unroll
        for (int rg = 0; rg < 4; ++rg)
          vb[nf][rg] = acc[mf][nf][rg] + bj4[nf];
#pragma unroll
      for (int rg = 0; rg < 4; ++rg) {
        float ss = vb[0][rg] * vb[0][rg];
        ss = __builtin_fmaf(vb[1][rg], vb[1][rg], ss);
        ss = __builtin_fmaf(vb[2][rg], vb[2][rg], ss);
        ss = __builtin_fmaf(vb[3][rg], vb[3][rg], ss);
        ss += __shfl_xor(ss, 1); ss += __shfl_xor(ss, 2);
        ss += __shfl_xor(ss, 4); ss += __shfl_xor(ss, 8);
        float f = rsqrtf(ss * (1.f / 64.f) + 1e-6f);
        int r = mf * 16 + 4 * g + rg;
#pragma unroll
        for (int nf = 0; nf < 4; ++nf) {
          int dl = nf * 16 + r15;
          Ep[r * 64 + (dl ^ ((r & 15) << 1))] = vb[nf][rg] * f * sl[nf];
        }
      }
    }
    WAITLGKM();
#pragma unroll
    for (int p2 = 0; p2 < 8; ++p2) {
      int r = 8 * p2 + (lane >> 3);
      int ch = lane & 7;
      int i = m0 + wm * 64 + r;
      int b = i >> rpbs;
      int pos = (i & rpbm) + posoff;
      union { uint32_t u[4]; s16x8 v; } o;
#pragma unroll
      for (int j = 0; j < 4; ++j) {
        f32x2 rd = *(const f32x2*)&Ep[r * 64 + ((ch * 8 + 2 * j) ^ ((r & 15) << 1))];
        o.u[j] = cvtpk(rd[0], rd[1]);
      }
      *(s16x8*)(dstb + ((size_t)((b * 16 + hh) * kNT + pos)) * 64 + ch * 8) = o.v;
    }
  }
}

// ---------- Flash attention: 4 waves x 32 q (QBLK=128), shared KV (dbuf, KVBLK=64) ----------
// ROUND-6 VERBATIM (56us / 1.46e-3 proven): 2-buffer, two barriers per tile,
// no-max softmax (RMSNorm-bounded), l via ones-MFMA, XCD-pinned heads.
__global__ __launch_bounds__(256, 3) void k_attn(
    const short* __restrict__ Q, const short* __restrict__ K,
    const short* __restrict__ Vt, short* __restrict__ Ao) {
  __shared__ __align__(16) short S[16384];  // 32 KB: K dbuf [0,8192), V dbuf [8192,16384)
  const int t = threadIdx.x;
  const int lane = t & 63, w = t >> 6;
  const int g = lane >> 4, r15 = lane & 15;
  const int lin = blockIdx.x;
  const int idx = lin >> 3;
  const int bh = (lin & 7) * 4 + idx / 18;
  const int q0 = (idx % 18) * 128;

  // Q B-fragments, 2 per wave (q = q0 + 32w + 16qi + r15); elem j -> d = 8g+j+32a
  s16x8 qf[2][2];
#pragma unroll
  for (int qi = 0; qi < 2; ++qi) {
    const short* qrow = Q + ((size_t)bh * kNT + q0 + 32 * w + 16 * qi + r15) * kD;
    qf[qi][0] = *(const s16x8*)(qrow + 8 * g);
    qf[qi][1] = *(const s16x8*)(qrow + 32 + 8 * g);
  }

  // staging: 512 16B-slots per matrix per tile, 2 per thread (4 gll/wave/tile)
  const short* kptr[2]; const short* vptr[2];
  int sb[2];
#pragma unroll
  for (int it = 0; it < 2; ++it) {
    int slot = t + 256 * it;
    int row = slot >> 3, gp = slot & 7;
    int gl = gp ^ (row & 7);
    kptr[it] = K + ((size_t)bh * kNT + row) * kD + 8 * gl;
    vptr[it] = Vt + ((size_t)bh * kD + row) * kNT + 8 * gl;
    sb[it] = (256 * it + 64 * w) * 8;
  }

  // hoisted LDS read offsets (element units)
  int ko[2][4], vo[2][4];
#pragma unroll
  for (int a = 0; a < 2; ++a)
#pragma unroll
    for (int rf = 0; rf < 4; ++rf) {
      int row = 16 * rf + r15;
      ko[a][rf] = row * 64 + (((g + 4 * a) ^ (row & 7)) * 8);
      vo[a][rf] = row * 64 + (((4 * a + g) ^ (row & 7)) * 8);
    }

  // all-ones bf16 A-fragment for the l-sum MFMA
  s16x8 onesf;
#pragma unroll
  for (int j = 0; j < 8; ++j) onesf[j] = (short)0x3F80;

  f32x4 ot0[4] = {}, ot1[4] = {};
  f32x4 ls0 = {}, ls1 = {};   // every element = l[q] at the end
  short* Kb0 = S;          short* Kb1 = S + 4096;
  short* Vb0 = S + 8192;   short* Vb1 = S + 12288;

  auto STAGE = [&](short* kst, short* vst) {
#pragma unroll
    for (int it = 0; it < 2; ++it) {
      gll16(kptr[it], kst + sb[it]);
      kptr[it] += 64 * kD;
    }
#pragma unroll
    for (int it = 0; it < 2; ++it) {
      gll16(vptr[it], vst + sb[it]);
      vptr[it] += 64;
    }
  };

  auto tile = [&](const short* Kb, const short* Vb, short* kst, short* vst,
                  bool last, bool pref) {
    if (last) WAITV0(); else WAITV4();   // this tile's 4 loads landed (per-wave)
    __builtin_amdgcn_s_barrier();
    FENCE();
    // S^T = K * Q^T for both q-frags (K frags shared)
    f32x4 st0[4] = {}, st1[4] = {};
    __builtin_amdgcn_s_setprio(1);
#pragma unroll
    for (int a = 0; a < 2; ++a) {
#pragma unroll
      for (int rf = 0; rf < 4; ++rf) {
        s16x8 kf = *(const s16x8*)(Kb + ko[a][rf]);
        st0[rf] = __builtin_amdgcn_mfma_f32_16x16x32_bf16(kf, qf[0][a], st0[rf], 0, 0, 0);
        st1[rf] = __builtin_amdgcn_mfma_f32_16x16x32_bf16(kf, qf[1][a], st1[rf], 0, 0, 0);
      }
    }
    __builtin_amdgcn_s_setprio(0);
    // softmax: pure exp2 (scale folded into q); no l adds (ones-MFMA below)
    float pv0[4][4], pv1[4][4];
#pragma unroll
    for (int rf = 0; rf < 4; ++rf)
#pragma unroll
      for (int j = 0; j < 4; ++j) {
        pv0[rf][j] = __builtin_amdgcn_exp2f(st0[rf][j]);
        pv1[rf][j] = __builtin_amdgcn_exp2f(st1[rf][j]);
      }
    // P^T pack: element j <-> kv = 32c + 4g + (j&3) + 16*(j>>2)
    s16x8 pf0[2], pf1[2];
#pragma unroll
    for (int c = 0; c < 2; ++c) {
      union { uint32_t u[4]; s16x8 v; } a, b;
      a.u[0] = cvtpk(pv0[2 * c][0], pv0[2 * c][1]);
      a.u[1] = cvtpk(pv0[2 * c][2], pv0[2 * c][3]);
      a.u[2] = cvtpk(pv0[2 * c + 1][0], pv0[2 * c + 1][1]);
      a.u[3] = cvtpk(pv0[2 * c + 1][2], pv0[2 * c + 1][3]);
      pf0[c] = a.v;
      b.u[0] = cvtpk(pv1[2 * c][0], pv1[2 * c][1]);
      b.u[1] = cvtpk(pv1[2 * c][2], pv1[2 * c][3]);
      b.u[2] = cvtpk(pv1[2 * c + 1][0], pv1[2 * c + 1][1]);
      b.u[3] = cvtpk(pv1[2 * c + 1][2], pv1[2 * c + 1][3]);
      pf1[c] = b.v;
    }
    // O^T += V^T * P^T (V frags shared by both q-frags); l-sum via ones-MFMA
    __builtin_amdgcn_s_setprio(1);
#pragma unroll
    for (int mf = 0; mf < 4; ++mf)
#pragma unroll
      for (int c = 0; c < 2; ++c) {
        s16x8 vf = *(const s16x8*)(Vb + vo[c][mf]);
        ot0[mf] = __builtin_amdgcn_mfma_f32_16x16x32_bf16(vf, pf0[c], ot0[mf], 0, 0, 0);
        ot1[mf] = __builtin_amdgcn_mfma_f32_16x16x32_bf16(vf, pf1[c], ot1[mf], 0, 0, 0);
      }
#pragma unroll
    for (int c = 0; c < 2; ++c) {
      ls0 = __builtin_amdgcn_mfma_f32_16x16x32_bf16(onesf, pf0[c], ls0, 0, 0, 0);
      ls1 = __builtin_amdgcn_mfma_f32_16x16x32_bf16(onesf, pf1[c], ls1, 0, 0, 0);
    }
    __builtin_amdgcn_s_setprio(0);
    FENCE();
    __builtin_amdgcn_s_barrier();        // all waves done reading this buffer
    FENCE();
    if (pref) STAGE(kst, vst);           // restage freed buffer (tile t+2)
  };

  // prologue: tiles 0,1 in flight
  STAGE(Kb0, Vb0);
  STAGE(Kb1, Vb1);
  for (int pp = 0; pp < 18; ++pp) {
    tile(Kb0, Vb0, Kb0, Vb0, false,    pp < 17);
    tile(Kb1, Vb1, Kb1, Vb1, pp == 17, pp < 17);
  }

  float rl0 = 1.f / ls0[0], rl1 = 1.f / ls1[0];

  // epilogue: transpose O^T -> O via LDS (reuse S as f32 [128 q][64 d]), coalesced store
  __syncthreads();
  float* Os = (float*)S;   // 8192 floats = 32 KB
#pragma unroll
  for (int mf = 0; mf < 4; ++mf)
#pragma unroll
    for (int rg = 0; rg < 4; ++rg) {
      int d = 16 * mf + 4 * g + rg;
      int R0 = 32 * w + r15, R1 = 32 * w + 16 + r15;
      Os[R0 * 64 + (d ^ ((r15 & 7) << 3))] = ot0[mf][rg] * rl0;
      Os[R1 * 64 + (d ^ ((r15 & 7) << 3))] = ot1[mf][rg] * rl1;
    }
  __syncthreads();
  {
    int b = bh >> 4, h = bh & 15;
#pragma unroll
    for (int rep = 0; rep < 2; ++rep) {
      int idx2 = t + 256 * rep;
      int q = idx2 >> 2, c4 = idx2 & 3;
      float vals[16];
#pragma unroll
      for (int i = 0; i < 4; ++i) {
        f32x4 rd = *(const f32x4*)&Os[q * 64 + (((c4 * 16 + 4 * i) ^ ((q & 7) << 3)))];
        vals[4 * i + 0] = rd[0]; vals[4 * i + 1] = rd[1];
        vals[4 * i + 2] = rd[2]; vals[4 * i + 3] = rd[3];
      }
      union { uint32_t u[4]; s16x8 v; } o0, o1;
      o0.u[0] = cvtpk(vals[0], vals[1]);   o0.u[1] = cvtpk(vals[2], vals[3]);
      o0.u[2] = cvtpk(vals[4], vals[5]);   o0.u[3] = cvtpk(vals[6], vals[7]);
      o1.u[0] = cvtpk(vals[8], vals[9]);   o1.u[1] = cvtpk(vals[10], vals[11]);
      o1.u[2] = cvtpk(vals[12], vals[13]); o1.u[3] = cvtpk(vals[14], vals[15]);
      short* dst = Ao + ((size_t)b * kNT + q0 + q) * kDIM + h * kD + c4 * 16;
      *(s16x8*)dst = o0.v;
      *(s16x8*)(dst + 8) = o1.v;
    }
  }
}

extern "C" void kernel_launch(void* const* d_in, const int* in_sizes, int n_in,
                              void* d_out, int out_size, void* d_ws, size_t ws_size,
                              hipStream_t stream) {
  const float* x   = (const float*)d_in[0];
  const float* c   = (const float*)d_in[1];
  const float* wqx = (const float*)d_in[2];
  const float* bqx = (const float*)d_in[3];
  const float* wqc = (const float*)d_in[4];
  const float* bqc = (const float*)d_in[5];
  const float* sqx = (const float*)d_in[6];
  const float* skx = (const float*)d_in[7];
  const float* sqc = (const float*)d_in[8];
  const float* skc = (const float*)d_in[9];
  const float* wpx = (const float*)d_in[10];
  const float* bpx = (const float*)d_in[11];
  const float* wpc = (const float*)d_in[12];
  const float* bpc = (const float*)d_in[13];
  float* out = (float*)d_out;

  char* p = (char*)d_ws;
  short* xb   = (short*)p; p += (size_t)4096 * 1024 * 2;
  short* cb   = (short*)p; p += (size_t)512 * 1024 * 2;
  short* wqxt = (short*)p; p += (size_t)3072 * 1024 * 2;
  short* wqct = (short*)p; p += (size_t)3072 * 1024 * 2;
  short* wpxt = (short*)p; p += (size_t)1024 * 1024 * 2;
  short* wpct = (short*)p; p += (size_t)1024 * 1024 * 2;
  short* qb   = (short*)p; p += (size_t)32 * 2304 * 64 * 2;
  short* kb   = (short*)p; p += (size_t)32 * 2304 * 64 * 2;
  short* vtb  = (short*)p; p += (size_t)32 * 64 * 2304 * 2;
  short* ao   = (short*)p; p += (size_t)2 * 2304 * 1024 * 2;

  k_cast2<<<4608, 256, 0, stream>>>(x, xb, c, cb, 4096);
  k_tcast2<<<dim3(96, 32, 2), dim3(32, 8), 0, stream>>>(wqx, wqxt, wqc, wqct, 1024, 3072);
  k_tcast2<<<dim3(32, 32, 2), dim3(32, 8), 0, stream>>>(wpx, wpxt, wpc, wpct, 1024, 1024);

  // QKV projections (+bias, fused RMSNorm; q pre-scaled by 0.125*log2e)
  k_gemm<<<864, 256, 0, stream>>>(
      xb, wqxt, bqx, sqx, skx,
      cb, wqct, bqc, sqc, skc,
      qb, kb, vtb, nullptr, nullptr,
      11, 2048, 0, 0,
      8, 256, 0, 2048,
      32, 0, 24);

  k_attn<<<576, 256, 0, stream>>>(qb, kb, vtb, ao);

  // output projections (f32 + bias) straight into d_out
  k_gemm<<<288, 256, 0, stream>>>(
      ao, wpxt, bpx, nullptr, nullptr,
      ao, wpct, bpc, nullptr, nullptr,
      nullptr, nullptr, nullptr, out, out + (size_t)4096 * 1024,
      11, 2304, 0, 0,
      8, 2304, 2048, 0,
      32, 1, 8);
}